// Round 5
// baseline (99.279 us; speedup 1.0000x reference)
//
#include <hip/hip_runtime.h>
#include <hip/hip_bf16.h>
#include <stdint.h>

#define DD 4
#define NVERT 5
#define NPTS 1024
#define BATCH 4
#define M0 5120           /* NPTS*NVERT */
#define CIN 64
#define COUT 64
#define NF 31
#define KTOT 1984         /* NF*CIN */
#define CAP 16384
#define CAPMASK (CAP-1)
#define SENTV 1073741824  /* 2^30, > any valid code (<128^4) */
#define ZROW (BATCH*M0)   /* zero row index in table_bf */

using bf16x8 = __attribute__((ext_vector_type(8))) short;
using f32x4  = __attribute__((ext_vector_type(4))) float;

__device__ __forceinline__ unsigned short f2bf(float x){
  unsigned int u = __float_as_uint(x);
  u = (u + 0x7FFFu + ((u >> 16) & 1u)) >> 16;
  return (unsigned short)u;
}

__device__ __forceinline__ uint32_t hslot(int code){
  return (((uint32_t)code * 2654435761u) >> 18) & CAPMASK;
}

// ============ setup: hash/table init + weight prep + data transpose =======
__global__ void k_setup(const float* __restrict__ wk, const float* __restrict__ data,
                        int* __restrict__ hc, int* __restrict__ hu, int* __restrict__ uc,
                        float4* __restrict__ table4, unsigned short* __restrict__ bp,
                        float* __restrict__ dat_t){
  int bid = blockIdx.x, tid = threadIdx.x;
  if (bid < 64){
    // ---- data transpose [b][c][n] -> dat_t [b*n][c] ----
    __shared__ float tile[64][65];
    int b = bid >> 4, n0 = (bid & 15) * 64;
    int nl = tid & 63;
    #pragma unroll
    for (int i = 0; i < 16; i++){
      int c = (tid >> 6) * 16 + i;
      tile[c][nl] = data[(((size_t)b * 64 + c) << 10) + n0 + nl];
    }
    __syncthreads();
    #pragma unroll
    for (int i = 0; i < 16; i++){
      int nn = (tid >> 6) * 16 + i;
      dat_t[(((size_t)b << 10) + n0 + nn) * 64 + (tid & 63)] = tile[tid & 63][nn];
    }
  } else if (bid < 560){
    // ---- weights -> Bprep[o][k] bf16, k = f*64 + c ----
    int e = (bid - 64) * 256 + tid;
    if (e < COUT * KTOT){
      int o = e / KTOT, k = e % KTOT;
      int f = k >> 6, c = k & 63;
      bp[e] = f2bf(wk[(o * CIN + c) * NF + f]);
    }
  } else {
    // ---- init hash + ucount + zero table ----
    int g = (bid - 560) * 256 + tid;
    int stride = 464 * 256;
    for (int i = g; i < BATCH * CAP; i += stride){ hc[i] = SENTV; hu[i] = -1; }
    if (g < BATCH) uc[g] = 0;
    float4 z = {0.f,0.f,0.f,0.f};
    for (int i = g; i < BATCH * M0 * CIN / 4; i += stride) table4[i] = z;
  }
}

// ============ per (point,vertex): simplex math + hash insert ==============
__global__ void k_points(const float* __restrict__ feat,
                         int* __restrict__ codes_pv, float* __restrict__ bary_pv,
                         int* __restrict__ hash_code){
  int g = blockIdx.x * blockDim.x + threadIdx.x;
  if (g >= BATCH * NPTS * NVERT) return;
  int p = g / NVERT, kk = g % NVERT;
  int b = p >> 10, n = p & 1023;
  const float* fb = feat + (size_t)b * DD * NPTS + n;
  float f0 = fb[0], f1 = fb[NPTS], f2 = fb[2 * NPTS], f3 = fb[3 * NPTS];

  float elev[5];
  elev[0] =  f0 * 2.886751345948129f  + f1 * 1.6666666666666667f + f2 * 1.1785113019775793f + f3 * 0.9128709291752769f;
  elev[1] = -f0 * 2.886751345948129f  + f1 * 1.6666666666666667f + f2 * 1.1785113019775793f + f3 * 0.9128709291752769f;
  elev[2] =  f1 * -3.3333333333333335f + f2 * 1.1785113019775793f + f3 * 0.9128709291752769f;
  elev[3] =  f2 * -3.535533905932738f  + f3 * 0.9128709291752769f;
  elev[4] =  f3 * -3.6514837167011076f;

  int gi[5]; float diff[5]; int sum = 0;
  #pragma unroll
  for (int i = 0; i < 5; i++){
    float gg = rintf(elev[i] * 0.2f) * 5.0f;
    gi[i] = (int)rintf(gg);
    sum += gi[i];
    diff[i] = elev[i] - gg;
  }
  int s = sum / 5;

  int rank[5];
  #pragma unroll
  for (int i = 0; i < 5; i++){
    int r = 0;
    #pragma unroll
    for (int j = 0; j < 5; j++)
      r += (diff[j] > diff[i]) || (diff[j] == diff[i] && j < i);
    rank[i] = r + s;
  }
  #pragma unroll
  for (int i = 0; i < 5; i++){
    if (rank[i] < 0)      { rank[i] += NVERT; gi[i] += NVERT; }
    else if (rank[i] > DD){ rank[i] -= NVERT; gi[i] -= NVERT; }
  }

  float bary[6] = {0.f,0.f,0.f,0.f,0.f,0.f};
  #pragma unroll
  for (int i = 0; i < 5; i++){
    float t = (elev[i] - (float)gi[i]) * 0.2f;
    bary[DD - rank[i]]    += t;
    bary[NVERT - rank[i]] += 1.0f - t;
  }
  bary[0] += 1.0f + bary[5];

  float bk = bary[0];
  #pragma unroll
  for (int i = 1; i < 5; i++) if (i == kk) bk = bary[i];

  int code = 0;
  #pragma unroll
  for (int j = 0; j < DD; j++){
    int add = (rank[j] >= NVERT - kk) ? (kk - NVERT) : kk;
    int key = gi[j] + add;
    key = min(63, max(-64, key));
    code += (key + 64) << (7 * j);
  }
  codes_pv[g] = code;
  bary_pv[g]  = bk;
  int* hc = hash_code + b * CAP;
  uint32_t h = hslot(code);
  while (true){
    int prev = atomicCAS(&hc[h], SENTV, code);
    if (prev == SENTV || prev == code) break;
    h = (h + 1) & CAPMASK;
  }
}

// ============ assign uids + decode unique keys ============================
__global__ void k_assign(const int* __restrict__ hash_code, int* __restrict__ hash_uid,
                         int* __restrict__ ucount, int* __restrict__ ukeys){
  int g = blockIdx.x * blockDim.x + threadIdx.x;
  if (g >= BATCH * CAP) return;
  int code = hash_code[g];
  if (code == SENTV) return;
  int b = g / CAP;
  int uid = atomicAdd(&ucount[b], 1);
  hash_uid[g] = uid;
  int* uk = ukeys + ((size_t)(b * M0 + uid)) * DD;
  #pragma unroll
  for (int j = 0; j < DD; j++) uk[j] = ((code >> (7 * j)) & 127) - 64;
}

// ============ splat: one wave per point, coalesced ========================
__global__ void k_splat(const float* __restrict__ dat_t, const int* __restrict__ codes_pv,
                        const float* __restrict__ bary_pv, const int* __restrict__ hash_code,
                        const int* __restrict__ hash_uid, int* __restrict__ idx_pv,
                        float* __restrict__ table){
  __shared__ int   us[4][8];
  __shared__ float wbs[4][8];
  int tid = threadIdx.x;
  int w = tid >> 6, lane = tid & 63;
  int p = blockIdx.x * 4 + w;
  int b = p >> 10;
  float v = dat_t[((size_t)p << 6) + lane];
  if (lane < NVERT){
    int code = codes_pv[p * NVERT + lane];
    const int* hc = hash_code + b * CAP;
    uint32_t h = hslot(code);
    while (hc[h] != code) h = (h + 1) & CAPMASK;
    int uid = hash_uid[b * CAP + h];
    us[w][lane]  = uid;
    wbs[w][lane] = bary_pv[p * NVERT + lane];
    idx_pv[p * NVERT + lane] = uid;
  }
  __syncthreads();
  #pragma unroll
  for (int kk = 0; kk < NVERT; kk++){
    atomicAdd(&table[(((size_t)(b * M0 + us[w][kk])) << 6) + lane], v * wbs[w][kk]);
  }
}

// ============ prep2: table->bf16 (+zero row)  AND  neighbor uid table =====
__global__ void k_prep2(const float* __restrict__ table, unsigned short* __restrict__ table_bf,
                        const int* __restrict__ ucount, const int* __restrict__ ukeys,
                        const int* __restrict__ hash_code, const int* __restrict__ hash_uid,
                        int* __restrict__ nuid){
  int bid = blockIdx.x, tid = threadIdx.x;
  if (bid < 640){
    int g = bid * 256 + tid;
    size_t base = (size_t)g * 8;
    const float4* s4 = (const float4*)(table + base);
    float4 x = s4[0], y = s4[1];
    bf16x8 v;
    v[0] = (short)f2bf(x.x); v[1] = (short)f2bf(x.y);
    v[2] = (short)f2bf(x.z); v[3] = (short)f2bf(x.w);
    v[4] = (short)f2bf(y.x); v[5] = (short)f2bf(y.y);
    v[6] = (short)f2bf(y.z); v[7] = (short)f2bf(y.w);
    *(bf16x8*)(table_bf + base) = v;
    if (g < 8){
      bf16x8 z = {0,0,0,0,0,0,0,0};
      *(bf16x8*)(table_bf + ((size_t)ZROW << 6) + g * 8) = z;
    }
  } else {
    // one thread per (b, m, f) lookup; e IS the nuid index
    int e = (bid - 640) * 256 + tid;            // [0, BATCH*M0*32)
    int f = e & 31;
    int idx = e >> 5;                           // b*M0 + m
    int b = idx / M0, m = idx - b * M0;
    int g = ZROW;
    if (f < NF && m < ucount[b]){
      const int* uk = ukeys + ((size_t)idx) * DD;
      int pc = __popc(f);
      int code = 0;
      #pragma unroll
      for (int j = 0; j < DD; j++){
        int key = uk[j] + 5 * ((f >> j) & 1) - pc;
        key = min(63, max(-64, key));
        code += (key + 64) << (7 * j);
      }
      const int* hc = hash_code + b * CAP;
      uint32_t h = hslot(code);
      while (true){
        int v = hc[h];
        if (v == code){ g = b * M0 + hash_uid[b * CAP + h]; break; }
        if (v == SENTV) break;
        h = (h + 1) & CAPMASK;
      }
    }
    nuid[e] = g;
  }
}

// ============ convolution: 16 waves, 4-way k-split, barrier-free MFMA =====
__launch_bounds__(1024)
__global__ void k_conv(const int* __restrict__ ucount, const int* __restrict__ nuid,
                       const unsigned short* __restrict__ table_bf,
                       const unsigned short* __restrict__ bp,
                       float* __restrict__ out_lat){
  __shared__ int gidx_s[64 * 33];
  __shared__ float red[3][4][64][17];

  int blk = blockIdx.x;
  int b   = blk / (M0 / 64);
  int m0  = (blk % (M0 / 64)) * 64;
  int ucnt = ucount[b];
  if (m0 >= ucnt) return;

  int tid = threadIdx.x;
  // coalesced load of the 64x32 neighbor-index tile
  {
    int base = (b * M0 + m0) << 5;
    #pragma unroll
    for (int i = 0; i < 2; i++){
      int idx = tid + i * 1024;
      gidx_s[(idx >> 5) * 33 + (idx & 31)] = nuid[base + idx];
    }
  }
  __syncthreads();

  int lane = tid & 63, wave = tid >> 6;
  int wm = wave & 1, wo = (wave >> 1) & 1, wk = wave >> 2;
  int arow = wm * 32 + (lane & 15);
  int acol = (lane >> 4) * 8;
  int bcol = wo * 32 + (lane & 15);
  const unsigned short* bpp0 = bp + (size_t)bcol * KTOT + acol;
  const unsigned short* bpp1 = bpp0 + (size_t)16 * KTOT;

  f32x4 acc00 = {0.f,0.f,0.f,0.f}, acc01 = {0.f,0.f,0.f,0.f};
  f32x4 acc10 = {0.f,0.f,0.f,0.f}, acc11 = {0.f,0.f,0.f,0.f};

  const int kstart[5] = {0, 16, 32, 47, 62};
  int ks0 = kstart[wk], ks1 = kstart[wk + 1];
  #pragma unroll 4
  for (int ks = ks0; ks < ks1; ks++){
    int f  = ks >> 1;
    int c0 = (ks & 1) << 5;
    int g0 = gidx_s[arow * 33 + f];
    int g1 = gidx_s[(arow + 16) * 33 + f];
    bf16x8 a0 = *(const bf16x8*)(table_bf + (((size_t)g0) << 6) + c0 + acol);
    bf16x8 a1 = *(const bf16x8*)(table_bf + (((size_t)g1) << 6) + c0 + acol);
    bf16x8 b0 = *(const bf16x8*)(bpp0 + (ks << 5));
    bf16x8 b1 = *(const bf16x8*)(bpp1 + (ks << 5));
    acc00 = __builtin_amdgcn_mfma_f32_16x16x32_bf16(a0, b0, acc00, 0, 0, 0);
    acc01 = __builtin_amdgcn_mfma_f32_16x16x32_bf16(a0, b1, acc01, 0, 0, 0);
    acc10 = __builtin_amdgcn_mfma_f32_16x16x32_bf16(a1, b0, acc10, 0, 0, 0);
    acc11 = __builtin_amdgcn_mfma_f32_16x16x32_bf16(a1, b1, acc11, 0, 0, 0);
  }

  int quad = wm * 2 + wo;
  if (wk > 0){
    #pragma unroll
    for (int q = 0; q < 4; q++){
      red[wk - 1][quad][lane][q]      = acc00[q];
      red[wk - 1][quad][lane][4 + q]  = acc01[q];
      red[wk - 1][quad][lane][8 + q]  = acc10[q];
      red[wk - 1][quad][lane][12 + q] = acc11[q];
    }
  }
  __syncthreads();
  if (wk == 0){
    #pragma unroll
    for (int r = 0; r < 3; r++){
      #pragma unroll
      for (int q = 0; q < 4; q++){
        acc00[q] += red[r][quad][lane][q];
        acc01[q] += red[r][quad][lane][4 + q];
        acc10[q] += red[r][quad][lane][8 + q];
        acc11[q] += red[r][quad][lane][12 + q];
      }
    }
    // C/D layout: col = lane&15, row = (lane>>4)*4 + q (m89-verified)
    int q4 = (lane >> 4) * 4, col = lane & 15;
    #pragma unroll
    for (int i = 0; i < 2; i++){
      f32x4 ai0 = (i == 0) ? acc00 : acc10;
      f32x4 ai1 = (i == 0) ? acc01 : acc11;
      #pragma unroll
      for (int q = 0; q < 4; q++){
        int m = m0 + wm * 32 + i * 16 + q4 + q;
        float* orow = out_lat + (((size_t)(b * M0 + m)) << 6);
        orow[wo * 32 + col]      = ai0[q];
        orow[wo * 32 + 16 + col] = ai1[q];
      }
    }
  }
}

// ============ slice + bias + transpose to [b][o][n] =======================
__global__ void k_slice(const float* __restrict__ bary_pv, const int* __restrict__ idx_pv,
                        const float* __restrict__ out_lat, const float* __restrict__ bias,
                        const float* __restrict__ bmul, float* __restrict__ out){
  __shared__ float tile[64][65];
  int b = blockIdx.x >> 4, n0 = (blockIdx.x & 15) * 64;
  int tid = threadIdx.x;
  int wave = tid >> 6, o = tid & 63;
  float bo = bias[o];
  #pragma unroll
  for (int i = 0; i < 16; i++){
    int n = wave * 16 + i;
    int p = (b << 10) + n0 + n;
    float acc = bo * bmul[n0 + n];
    int base = p * NVERT;
    #pragma unroll
    for (int kk = 0; kk < NVERT; kk++){
      int u = idx_pv[base + kk];
      acc += bary_pv[base + kk] * out_lat[(((size_t)(b * M0 + u)) << 6) + o];
    }
    tile[n][o] = acc;
  }
  __syncthreads();
  int nl = tid & 63, ob = (tid >> 6) * 16;
  #pragma unroll
  for (int i = 0; i < 16; i++){
    int o2 = ob + i;
    out[(((size_t)b * 64 + o2) << 10) + n0 + nl] = tile[nl][o2];
  }
}

extern "C" void kernel_launch(void* const* d_in, const int* in_sizes, int n_in,
                              void* d_out, int out_size, void* d_ws, size_t ws_size,
                              hipStream_t stream){
  const float* data = (const float*)d_in[0];
  const float* feat = (const float*)d_in[1];
  const float* wk   = (const float*)d_in[2];
  const float* bias = (const float*)d_in[3];
  const float* bmul = (const float*)d_in[4];
  float* out = (float*)d_out;

  char* ws = (char*)d_ws;
  size_t off = 0;
  auto alloc = [&](size_t bytes){
    void* p = ws + off;
    off = (off + bytes + 255) & ~(size_t)255;
    return p;
  };
  int*   codes_pv = (int*)  alloc((size_t)BATCH * M0 * 4);
  float* bary_pv  = (float*)alloc((size_t)BATCH * M0 * 4);
  int*   idx_pv   = (int*)  alloc((size_t)BATCH * M0 * 4);
  int*   hash_code= (int*)  alloc((size_t)BATCH * CAP * 4);
  int*   hash_uid = (int*)  alloc((size_t)BATCH * CAP * 4);
  int*   ucount   = (int*)  alloc(256);
  int*   ukeys    = (int*)  alloc((size_t)BATCH * M0 * DD * 4);
  float* table    = (float*)alloc((size_t)BATCH * M0 * CIN * 4);
  float* out_lat  = (float*)alloc((size_t)BATCH * M0 * COUT * 4);
  unsigned short* bp       = (unsigned short*)alloc((size_t)COUT * KTOT * 2);
  unsigned short* table_bf = (unsigned short*)alloc(((size_t)BATCH * M0 + 8) * CIN * 2);
  float* dat_t    = (float*)alloc((size_t)BATCH * NPTS * CIN * 4);
  int*   nuid     = (int*)  alloc((size_t)BATCH * M0 * 32 * 4);

  k_setup <<<1024, 256, 0, stream>>>(wk, data, hash_code, hash_uid, ucount,
                                     (float4*)table, bp, dat_t);
  k_points<<<BATCH * NPTS * NVERT / 256, 256, 0, stream>>>(feat, codes_pv, bary_pv, hash_code);
  k_assign<<<BATCH * CAP / 256, 256, 0, stream>>>(hash_code, hash_uid, ucount, ukeys);
  k_splat <<<BATCH * NPTS / 4, 256, 0, stream>>>(dat_t, codes_pv, bary_pv, hash_code, hash_uid, idx_pv, table);
  k_prep2 <<<640 + BATCH * M0 * 32 / 256, 256, 0, stream>>>(table, table_bf, ucount, ukeys,
                                                            hash_code, hash_uid, nuid);
  k_conv  <<<BATCH * (M0 / 64), 1024, 0, stream>>>(ucount, nuid, table_bf, bp, out_lat);
  k_slice <<<BATCH * 16, 256, 0, stream>>>(bary_pv, idx_pv, out_lat, bias, bmul, out);
}

// Round 6
// 93.408 us; speedup vs baseline: 1.0629x; 1.0629x over previous
//
#include <hip/hip_runtime.h>
#include <hip/hip_bf16.h>
#include <stdint.h>

#define DD 4
#define NVERT 5
#define NPTS 1024
#define BATCH 4
#define M0 5120           /* NPTS*NVERT */
#define CIN 64
#define COUT 64
#define NF 31
#define KTOT 1984         /* NF*CIN */
#define CAP 16384
#define CAPMASK (CAP-1)
#define SENTV 1073741824  /* 2^30, > any valid code (<128^4) */
#define ZROW (BATCH*M0)   /* zero row index in table_bf */

using bf16x8 = __attribute__((ext_vector_type(8))) short;
using f32x4  = __attribute__((ext_vector_type(4))) float;

__device__ __forceinline__ unsigned short f2bf(float x){
  unsigned int u = __float_as_uint(x);
  u = (u + 0x7FFFu + ((u >> 16) & 1u)) >> 16;
  return (unsigned short)u;
}

__device__ __forceinline__ uint32_t hslot(int code){
  return (((uint32_t)code * 2654435761u) >> 18) & CAPMASK;
}

// ============ setup: hash/table init + weight prep + data transpose =======
__global__ void k_setup(const float* __restrict__ wk, const float* __restrict__ data,
                        int* __restrict__ hc, int* __restrict__ hu, int* __restrict__ uc,
                        float4* __restrict__ table4, unsigned short* __restrict__ bp,
                        float* __restrict__ dat_t){
  int bid = blockIdx.x, tid = threadIdx.x;
  if (bid < 64){
    // ---- data transpose [b][c][n] -> dat_t [b*n][c] ----
    __shared__ float tile[64][65];
    int b = bid >> 4, n0 = (bid & 15) * 64;
    int nl = tid & 63;
    #pragma unroll
    for (int i = 0; i < 16; i++){
      int c = (tid >> 6) * 16 + i;
      tile[c][nl] = data[(((size_t)b * 64 + c) << 10) + n0 + nl];
    }
    __syncthreads();
    #pragma unroll
    for (int i = 0; i < 16; i++){
      int nn = (tid >> 6) * 16 + i;
      dat_t[(((size_t)b << 10) + n0 + nn) * 64 + (tid & 63)] = tile[tid & 63][nn];
    }
  } else if (bid < 560){
    // ---- weights -> Bprep[o][k] bf16, k = f*64 + c ----
    int e = (bid - 64) * 256 + tid;
    if (e < COUT * KTOT){
      int o = e / KTOT, k = e % KTOT;
      int f = k >> 6, c = k & 63;
      bp[e] = f2bf(wk[(o * CIN + c) * NF + f]);
    }
  } else {
    // ---- init hash + ucount + zero table ----
    int g = (bid - 560) * 256 + tid;
    int stride = 464 * 256;
    for (int i = g; i < BATCH * CAP; i += stride){ hc[i] = SENTV; hu[i] = -1; }
    if (g < BATCH) uc[g] = 0;
    float4 z = {0.f,0.f,0.f,0.f};
    for (int i = g; i < BATCH * M0 * CIN / 4; i += stride) table4[i] = z;
  }
}

// ============ per (point,vertex): simplex math + dedup insert + uid =======
__global__ void k_points(const float* __restrict__ feat,
                         int* __restrict__ codes_pv, float* __restrict__ bary_pv,
                         int* __restrict__ hash_code, int* __restrict__ hash_uid,
                         int* __restrict__ ucount, int* __restrict__ ukeys){
  __shared__ int lhash[512];
  int tid = threadIdx.x;
  lhash[tid] = SENTV; lhash[tid + 256] = SENTV;
  __syncthreads();

  int g = blockIdx.x * 256 + tid;                 // pv index; blocks never straddle batches
  int p = g / NVERT, kk = g % NVERT;
  int b = p >> 10, n = p & 1023;
  const float* fb = feat + (size_t)b * DD * NPTS + n;
  float f0 = fb[0], f1 = fb[NPTS], f2 = fb[2 * NPTS], f3 = fb[3 * NPTS];

  float elev[5];
  elev[0] =  f0 * 2.886751345948129f  + f1 * 1.6666666666666667f + f2 * 1.1785113019775793f + f3 * 0.9128709291752769f;
  elev[1] = -f0 * 2.886751345948129f  + f1 * 1.6666666666666667f + f2 * 1.1785113019775793f + f3 * 0.9128709291752769f;
  elev[2] =  f1 * -3.3333333333333335f + f2 * 1.1785113019775793f + f3 * 0.9128709291752769f;
  elev[3] =  f2 * -3.535533905932738f  + f3 * 0.9128709291752769f;
  elev[4] =  f3 * -3.6514837167011076f;

  int gi[5]; float diff[5]; int sum = 0;
  #pragma unroll
  for (int i = 0; i < 5; i++){
    float gg = rintf(elev[i] * 0.2f) * 5.0f;
    gi[i] = (int)rintf(gg);
    sum += gi[i];
    diff[i] = elev[i] - gg;
  }
  int s = sum / 5;

  int rank[5];
  #pragma unroll
  for (int i = 0; i < 5; i++){
    int r = 0;
    #pragma unroll
    for (int j = 0; j < 5; j++)
      r += (diff[j] > diff[i]) || (diff[j] == diff[i] && j < i);
    rank[i] = r + s;
  }
  #pragma unroll
  for (int i = 0; i < 5; i++){
    if (rank[i] < 0)      { rank[i] += NVERT; gi[i] += NVERT; }
    else if (rank[i] > DD){ rank[i] -= NVERT; gi[i] -= NVERT; }
  }

  float bary[6] = {0.f,0.f,0.f,0.f,0.f,0.f};
  #pragma unroll
  for (int i = 0; i < 5; i++){
    float t = (elev[i] - (float)gi[i]) * 0.2f;
    bary[DD - rank[i]]    += t;
    bary[NVERT - rank[i]] += 1.0f - t;
  }
  bary[0] += 1.0f + bary[5];

  float bk = bary[0];
  #pragma unroll
  for (int i = 1; i < 5; i++) if (i == kk) bk = bary[i];

  int code = 0;
  #pragma unroll
  for (int j = 0; j < DD; j++){
    int add = (rank[j] >= NVERT - kk) ? (kk - NVERT) : kk;
    int key = gi[j] + add;
    key = min(63, max(-64, key));
    code += (key + 64) << (7 * j);
  }
  codes_pv[g] = code;
  bary_pv[g]  = bk;

  // ---- per-block LDS dedupe: only one thread per distinct code goes global
  uint32_t lh = (((uint32_t)code * 2654435761u) >> 21) & 511;
  bool winner = false;
  while (true){
    int prev = atomicCAS(&lhash[lh], SENTV, code);
    if (prev == SENTV){ winner = true; break; }
    if (prev == code) break;
    lh = (lh + 1) & 511;
  }
  if (winner){
    int* hc = hash_code + b * CAP;
    uint32_t h = hslot(code);
    while (true){
      int prev = atomicCAS(&hc[h], SENTV, code);
      if (prev == SENTV){
        int uid = atomicAdd(&ucount[b], 1);
        hash_uid[b * CAP + h] = uid;
        int* uk = ukeys + ((size_t)(b * M0 + uid)) * DD;
        #pragma unroll
        for (int j = 0; j < DD; j++) uk[j] = ((code >> (7 * j)) & 127) - 64;
        break;
      }
      if (prev == code) break;
      h = (h + 1) & CAPMASK;
    }
  }
}

// ============ fused: splat (blocks < 1024) + neighbor lookups (rest) ======
__global__ void k_sn(const float* __restrict__ dat_t, const int* __restrict__ codes_pv,
                     const float* __restrict__ bary_pv, const int* __restrict__ hash_code,
                     const int* __restrict__ hash_uid, const int* __restrict__ ucount,
                     const int* __restrict__ ukeys,
                     int* __restrict__ idx_pv, float* __restrict__ table,
                     int* __restrict__ nuid){
  int bid = blockIdx.x, tid = threadIdx.x;
  if (bid < BATCH * NPTS / 4){
    // ---- splat: one wave per point, coalesced ----
    __shared__ int   us[4][8];
    __shared__ float wbs[4][8];
    int w = tid >> 6, lane = tid & 63;
    int p = bid * 4 + w;
    int b = p >> 10;
    float v = dat_t[((size_t)p << 6) + lane];
    if (lane < NVERT){
      int code = codes_pv[p * NVERT + lane];
      const int* hc = hash_code + b * CAP;
      uint32_t h = hslot(code);
      while (hc[h] != code) h = (h + 1) & CAPMASK;
      int uid = hash_uid[b * CAP + h];
      us[w][lane]  = uid;
      wbs[w][lane] = bary_pv[p * NVERT + lane];
      idx_pv[p * NVERT + lane] = uid;
    }
    __syncthreads();
    int rot = p % NVERT;                     // stagger to spread same-row atomics
    #pragma unroll
    for (int kq = 0; kq < NVERT; kq++){
      int kk = kq + rot; if (kk >= NVERT) kk -= NVERT;
      atomicAdd(&table[(((size_t)(b * M0 + us[w][kk])) << 6) + lane], v * wbs[w][kk]);
    }
  } else {
    // ---- neighbor uid lookup: one thread per (vertex, filter-offset) ----
    int e = (bid - BATCH * NPTS / 4) * 256 + tid;   // [0, BATCH*M0*32)
    int f = e & 31;
    int idx = e >> 5;                               // b*M0 + m
    int b = idx / M0, m = idx - b * M0;
    int g = ZROW;
    if (f < NF && m < ucount[b]){
      const int* uk = ukeys + ((size_t)idx) * DD;
      int pc = __popc(f);
      int code = 0;
      #pragma unroll
      for (int j = 0; j < DD; j++){
        int key = uk[j] + 5 * ((f >> j) & 1) - pc;
        key = min(63, max(-64, key));
        code += (key + 64) << (7 * j);
      }
      const int* hc = hash_code + b * CAP;
      uint32_t h = hslot(code);
      while (true){
        int v = hc[h];
        if (v == code){ g = b * M0 + hash_uid[b * CAP + h]; break; }
        if (v == SENTV) break;
        h = (h + 1) & CAPMASK;
      }
    }
    nuid[e] = g;
  }
}

// ============ table fp32 -> bf16 (+ zero row) ==============================
__global__ void k_tobf(const float* __restrict__ table, unsigned short* __restrict__ table_bf){
  int g = blockIdx.x * blockDim.x + threadIdx.x;
  size_t base = (size_t)g * 8;
  const float4* s4 = (const float4*)(table + base);
  float4 x = s4[0], y = s4[1];
  bf16x8 v;
  v[0] = (short)f2bf(x.x); v[1] = (short)f2bf(x.y);
  v[2] = (short)f2bf(x.z); v[3] = (short)f2bf(x.w);
  v[4] = (short)f2bf(y.x); v[5] = (short)f2bf(y.y);
  v[6] = (short)f2bf(y.z); v[7] = (short)f2bf(y.w);
  *(bf16x8*)(table_bf + base) = v;
  if (g < 8){
    bf16x8 z = {0,0,0,0,0,0,0,0};
    *(bf16x8*)(table_bf + ((size_t)ZROW << 6) + g * 8) = z;
  }
}

// ============ convolution: 8 waves, 2-way k-split, barrier-free MFMA ======
__launch_bounds__(512)
__global__ void k_conv(const int* __restrict__ ucount, const int* __restrict__ nuid,
                       const unsigned short* __restrict__ table_bf,
                       const unsigned short* __restrict__ bp,
                       float* __restrict__ out_lat){
  __shared__ int gidx_s[64 * 33];
  __shared__ float red[4][64][17];

  int blk = blockIdx.x;
  int b   = blk / (M0 / 64);
  int m0  = (blk % (M0 / 64)) * 64;
  if (m0 >= ucount[b]) return;

  int tid = threadIdx.x;
  {
    int base = (b * M0 + m0) << 5;
    #pragma unroll
    for (int i = 0; i < 4; i++){
      int idx = tid + i * 512;
      gidx_s[(idx >> 5) * 33 + (idx & 31)] = nuid[base + idx];
    }
  }
  __syncthreads();

  int lane = tid & 63, wave = tid >> 6;
  int wm = wave & 1, wo = (wave >> 1) & 1, wk = wave >> 2;
  int arow = wm * 32 + (lane & 15);
  int acol = (lane >> 4) * 8;
  int bcol = wo * 32 + (lane & 15);
  const unsigned short* bpp0 = bp + (size_t)bcol * KTOT + acol;
  const unsigned short* bpp1 = bpp0 + (size_t)16 * KTOT;

  f32x4 acc00 = {0.f,0.f,0.f,0.f}, acc01 = {0.f,0.f,0.f,0.f};
  f32x4 acc10 = {0.f,0.f,0.f,0.f}, acc11 = {0.f,0.f,0.f,0.f};

  int ks0 = wk * 32, ks1 = wk ? 62 : 32;
  #pragma unroll 4
  for (int ks = ks0; ks < ks1; ks++){
    int f  = ks >> 1;
    int c0 = (ks & 1) << 5;
    int g0 = gidx_s[arow * 33 + f];
    int g1 = gidx_s[(arow + 16) * 33 + f];
    bf16x8 a0 = *(const bf16x8*)(table_bf + (((size_t)g0) << 6) + c0 + acol);
    bf16x8 a1 = *(const bf16x8*)(table_bf + (((size_t)g1) << 6) + c0 + acol);
    bf16x8 b0 = *(const bf16x8*)(bpp0 + (ks << 5));
    bf16x8 b1 = *(const bf16x8*)(bpp1 + (ks << 5));
    acc00 = __builtin_amdgcn_mfma_f32_16x16x32_bf16(a0, b0, acc00, 0, 0, 0);
    acc01 = __builtin_amdgcn_mfma_f32_16x16x32_bf16(a0, b1, acc01, 0, 0, 0);
    acc10 = __builtin_amdgcn_mfma_f32_16x16x32_bf16(a1, b0, acc10, 0, 0, 0);
    acc11 = __builtin_amdgcn_mfma_f32_16x16x32_bf16(a1, b1, acc11, 0, 0, 0);
  }

  int wl = wave & 3;
  if (wk == 1){
    #pragma unroll
    for (int q = 0; q < 4; q++){
      red[wl][lane][q]      = acc00[q];
      red[wl][lane][4 + q]  = acc01[q];
      red[wl][lane][8 + q]  = acc10[q];
      red[wl][lane][12 + q] = acc11[q];
    }
  }
  __syncthreads();
  if (wk == 0){
    #pragma unroll
    for (int q = 0; q < 4; q++){
      acc00[q] += red[wl][lane][q];
      acc01[q] += red[wl][lane][4 + q];
      acc10[q] += red[wl][lane][8 + q];
      acc11[q] += red[wl][lane][12 + q];
    }
    // C/D layout: col = lane&15, row = (lane>>4)*4 + q (m89-verified)
    int q4 = (lane >> 4) * 4, col = lane & 15;
    #pragma unroll
    for (int i = 0; i < 2; i++){
      f32x4 ai0 = (i == 0) ? acc00 : acc10;
      f32x4 ai1 = (i == 0) ? acc01 : acc11;
      #pragma unroll
      for (int q = 0; q < 4; q++){
        int m = m0 + wm * 32 + i * 16 + q4 + q;
        float* orow = out_lat + (((size_t)(b * M0 + m)) << 6);
        orow[wo * 32 + col]      = ai0[q];
        orow[wo * 32 + 16 + col] = ai1[q];
      }
    }
  }
}

// ============ slice + bias + transpose to [b][o][n], 32-row tiles =========
__global__ void k_slice(const float* __restrict__ bary_pv, const int* __restrict__ idx_pv,
                        const float* __restrict__ out_lat, const float* __restrict__ bias,
                        const float* __restrict__ bmul, float* __restrict__ out){
  __shared__ float tile[32][65];
  int b = blockIdx.x >> 5, n0 = (blockIdx.x & 31) * 32;
  int tid = threadIdx.x;
  int wave = tid >> 6, o = tid & 63;
  float bo = bias[o];
  #pragma unroll
  for (int i = 0; i < 8; i++){
    int n = wave * 8 + i;
    int p = (b << 10) + n0 + n;
    float acc = bo * bmul[n0 + n];
    int base = p * NVERT;
    #pragma unroll
    for (int kk = 0; kk < NVERT; kk++){
      int u = idx_pv[base + kk];
      acc += bary_pv[base + kk] * out_lat[(((size_t)(b * M0 + u)) << 6) + o];
    }
    tile[n][o] = acc;
  }
  __syncthreads();
  int nl = tid & 31, ob = (tid >> 5) * 8;
  #pragma unroll
  for (int i = 0; i < 8; i++){
    int o2 = ob + i;
    out[(((size_t)b * 64 + o2) << 10) + n0 + nl] = tile[nl][o2];
  }
}

extern "C" void kernel_launch(void* const* d_in, const int* in_sizes, int n_in,
                              void* d_out, int out_size, void* d_ws, size_t ws_size,
                              hipStream_t stream){
  const float* data = (const float*)d_in[0];
  const float* feat = (const float*)d_in[1];
  const float* wk   = (const float*)d_in[2];
  const float* bias = (const float*)d_in[3];
  const float* bmul = (const float*)d_in[4];
  float* out = (float*)d_out;

  char* ws = (char*)d_ws;
  size_t off = 0;
  auto alloc = [&](size_t bytes){
    void* p = ws + off;
    off = (off + bytes + 255) & ~(size_t)255;
    return p;
  };
  int*   codes_pv = (int*)  alloc((size_t)BATCH * M0 * 4);
  float* bary_pv  = (float*)alloc((size_t)BATCH * M0 * 4);
  int*   idx_pv   = (int*)  alloc((size_t)BATCH * M0 * 4);
  int*   hash_code= (int*)  alloc((size_t)BATCH * CAP * 4);
  int*   hash_uid = (int*)  alloc((size_t)BATCH * CAP * 4);
  int*   ucount   = (int*)  alloc(256);
  int*   ukeys    = (int*)  alloc((size_t)BATCH * M0 * DD * 4);
  float* table    = (float*)alloc((size_t)BATCH * M0 * CIN * 4);
  float* out_lat  = (float*)alloc((size_t)BATCH * M0 * COUT * 4);
  unsigned short* bp       = (unsigned short*)alloc((size_t)COUT * KTOT * 2);
  unsigned short* table_bf = (unsigned short*)alloc(((size_t)BATCH * M0 + 8) * CIN * 2);
  float* dat_t    = (float*)alloc((size_t)BATCH * NPTS * CIN * 4);
  int*   nuid     = (int*)  alloc((size_t)BATCH * M0 * 32 * 4);

  k_setup <<<1024, 256, 0, stream>>>(wk, data, hash_code, hash_uid, ucount,
                                     (float4*)table, bp, dat_t);
  k_points<<<BATCH * NPTS * NVERT / 256, 256, 0, stream>>>(feat, codes_pv, bary_pv,
                                                           hash_code, hash_uid, ucount, ukeys);
  k_sn    <<<BATCH * NPTS / 4 + BATCH * M0 * 32 / 256, 256, 0, stream>>>(
            dat_t, codes_pv, bary_pv, hash_code, hash_uid, ucount, ukeys,
            idx_pv, table, nuid);
  k_tobf  <<<BATCH * M0 * CIN / 8 / 256, 256, 0, stream>>>(table, table_bf);
  k_conv  <<<BATCH * (M0 / 64), 512, 0, stream>>>(ucount, nuid, table_bf, bp, out_lat);
  k_slice <<<BATCH * 32, 256, 0, stream>>>(bary_pv, idx_pv, out_lat, bias, bmul, out);
}

// Round 7
// 64.365 us; speedup vs baseline: 1.5424x; 1.4512x over previous
//
#include <hip/hip_runtime.h>
#include <hip/hip_bf16.h>
#include <stdint.h>

#define DD 4
#define NVERT 5
#define NPTS 1024
#define BATCH 4
#define M0 5120           /* NPTS*NVERT */
#define CIN 64
#define COUT 64
#define NF 31
#define KTOT 1984         /* NF*CIN */
#define CAP 16384
#define CAPMASK (CAP-1)
#define SENTV 1073741824  /* 2^30, > any valid code (<128^4) */
#define ZROW (BATCH*M0)   /* zero row index in table_bf */

using bf16x8 = __attribute__((ext_vector_type(8))) short;
using f32x4  = __attribute__((ext_vector_type(4))) float;

__device__ __forceinline__ unsigned short f2bf(float x){
  unsigned int u = __float_as_uint(x);
  u = (u + 0x7FFFu + ((u >> 16) & 1u)) >> 16;
  return (unsigned short)u;
}

__device__ __forceinline__ uint32_t hslot(int code){
  return (((uint32_t)code * 2654435761u) >> 18) & CAPMASK;
}

// ============ setup: hash/table init + weight prep + data transpose =======
__global__ void k_setup(const float* __restrict__ wk, const float* __restrict__ data,
                        int* __restrict__ hc, int* __restrict__ hu, int* __restrict__ uc,
                        float4* __restrict__ table4, unsigned short* __restrict__ bp,
                        float* __restrict__ dat_t){
  int bid = blockIdx.x, tid = threadIdx.x;
  if (bid < 64){
    // ---- data transpose [b][c][n] -> dat_t [b*n][c] ----
    __shared__ float tile[64][65];
    int b = bid >> 4, n0 = (bid & 15) * 64;
    int nl = tid & 63;
    #pragma unroll
    for (int i = 0; i < 16; i++){
      int c = (tid >> 6) * 16 + i;
      tile[c][nl] = data[(((size_t)b * 64 + c) << 10) + n0 + nl];
    }
    __syncthreads();
    #pragma unroll
    for (int i = 0; i < 16; i++){
      int nn = (tid >> 6) * 16 + i;
      dat_t[(((size_t)b << 10) + n0 + nn) * 64 + (tid & 63)] = tile[tid & 63][nn];
    }
  } else if (bid < 560){
    // ---- weights -> Bprep[o][k] bf16, k = f*64 + c ----
    int e = (bid - 64) * 256 + tid;
    if (e < COUT * KTOT){
      int o = e / KTOT, k = e % KTOT;
      int f = k >> 6, c = k & 63;
      bp[e] = f2bf(wk[(o * CIN + c) * NF + f]);
    }
  } else {
    // ---- init hash + ucount + zero table ----
    int g = (bid - 560) * 256 + tid;
    int stride = 464 * 256;
    for (int i = g; i < BATCH * CAP; i += stride){ hc[i] = SENTV; hu[i] = -1; }
    if (g < BATCH) uc[g] = 0;
    float4 z = {0.f,0.f,0.f,0.f};
    for (int i = g; i < BATCH * M0 * CIN / 4; i += stride) table4[i] = z;
  }
}

// ============ per (point,vertex): simplex math only (no atomics) ==========
__global__ void k_pmath(const float* __restrict__ feat,
                        int* __restrict__ codes_pv, float* __restrict__ bary_pv){
  int g = blockIdx.x * 256 + threadIdx.x;
  int p = g / NVERT, kk = g % NVERT;
  int b = p >> 10, n = p & 1023;
  const float* fb = feat + (size_t)b * DD * NPTS + n;
  float f0 = fb[0], f1 = fb[NPTS], f2 = fb[2 * NPTS], f3 = fb[3 * NPTS];

  float elev[5];
  elev[0] =  f0 * 2.886751345948129f  + f1 * 1.6666666666666667f + f2 * 1.1785113019775793f + f3 * 0.9128709291752769f;
  elev[1] = -f0 * 2.886751345948129f  + f1 * 1.6666666666666667f + f2 * 1.1785113019775793f + f3 * 0.9128709291752769f;
  elev[2] =  f1 * -3.3333333333333335f + f2 * 1.1785113019775793f + f3 * 0.9128709291752769f;
  elev[3] =  f2 * -3.535533905932738f  + f3 * 0.9128709291752769f;
  elev[4] =  f3 * -3.6514837167011076f;

  int gi[5]; float diff[5]; int sum = 0;
  #pragma unroll
  for (int i = 0; i < 5; i++){
    float gg = rintf(elev[i] * 0.2f) * 5.0f;
    gi[i] = (int)rintf(gg);
    sum += gi[i];
    diff[i] = elev[i] - gg;
  }
  int s = sum / 5;

  int rank[5];
  #pragma unroll
  for (int i = 0; i < 5; i++){
    int r = 0;
    #pragma unroll
    for (int j = 0; j < 5; j++)
      r += (diff[j] > diff[i]) || (diff[j] == diff[i] && j < i);
    rank[i] = r + s;
  }
  #pragma unroll
  for (int i = 0; i < 5; i++){
    if (rank[i] < 0)      { rank[i] += NVERT; gi[i] += NVERT; }
    else if (rank[i] > DD){ rank[i] -= NVERT; gi[i] -= NVERT; }
  }

  float bary[6] = {0.f,0.f,0.f,0.f,0.f,0.f};
  #pragma unroll
  for (int i = 0; i < 5; i++){
    float t = (elev[i] - (float)gi[i]) * 0.2f;
    bary[DD - rank[i]]    += t;
    bary[NVERT - rank[i]] += 1.0f - t;
  }
  bary[0] += 1.0f + bary[5];

  float bk = bary[0];
  #pragma unroll
  for (int i = 1; i < 5; i++) if (i == kk) bk = bary[i];

  int code = 0;
  #pragma unroll
  for (int j = 0; j < DD; j++){
    int add = (rank[j] >= NVERT - kk) ? (kk - NVERT) : kk;
    int key = gi[j] + add;
    key = min(63, max(-64, key));
    code += (key + 64) << (7 * j);
  }
  codes_pv[g] = code;
  bary_pv[g]  = bk;
}

// ============ insert: LDS dedupe + global CAS + wave-aggregated uid =======
__global__ void k_insert(const int* __restrict__ codes_pv,
                         int* __restrict__ hash_code, int* __restrict__ hash_uid,
                         int* __restrict__ ucount, int* __restrict__ ukeys){
  __shared__ int lhash[512];
  int tid = threadIdx.x;
  lhash[tid] = SENTV; lhash[tid + 256] = SENTV;
  __syncthreads();

  int g = blockIdx.x * 256 + tid;       // blocks never straddle batches (5120/256=20)
  int b = g / M0;
  int code = codes_pv[g];

  // per-block LDS dedupe: one representative per distinct code per block
  uint32_t lh = (((uint32_t)code * 2654435761u) >> 21) & 511;
  bool rep = false;
  while (true){
    int prev = atomicCAS(&lhash[lh], SENTV, code);
    if (prev == SENTV){ rep = true; break; }
    if (prev == code) break;
    lh = (lh + 1) & 511;
  }

  // global insert; myslot >= 0 iff this thread claimed the slot (global winner)
  int myslot = -1;
  if (rep){
    int* hc = hash_code + b * CAP;
    uint32_t h = hslot(code);
    while (true){
      int prev = atomicCAS(&hc[h], SENTV, code);
      if (prev == SENTV){ myslot = (int)h; break; }
      if (prev == code) break;
      h = (h + 1) & CAPMASK;
    }
  }

  // wave-aggregated uid allocation: one atomicAdd per wave (not per winner)
  unsigned long long mask = __ballot(myslot >= 0);
  if (mask){
    int lane = tid & 63;
    int cnt = __popcll(mask);
    int leader = __ffsll((unsigned long long)mask) - 1;
    int base = 0;
    if (lane == leader) base = atomicAdd(&ucount[b], cnt);
    base = __shfl(base, leader);
    if (myslot >= 0){
      int rank = __popcll(mask & ((1ull << lane) - 1ull));
      int uid = base + rank;
      hash_uid[b * CAP + myslot] = uid;
      int* uk = ukeys + ((size_t)(b * M0 + uid)) * DD;
      #pragma unroll
      for (int j = 0; j < DD; j++) uk[j] = ((code >> (7 * j)) & 127) - 64;
    }
  }
}

// ============ fused: splat (blocks < 1024) + neighbor lookups (rest) ======
__global__ void k_sn(const float* __restrict__ dat_t, const int* __restrict__ codes_pv,
                     const float* __restrict__ bary_pv, const int* __restrict__ hash_code,
                     const int* __restrict__ hash_uid, const int* __restrict__ ucount,
                     const int* __restrict__ ukeys,
                     int* __restrict__ idx_pv, float* __restrict__ table,
                     int* __restrict__ nuid){
  int bid = blockIdx.x, tid = threadIdx.x;
  if (bid < BATCH * NPTS / 4){
    // ---- splat: one wave per point, coalesced ----
    __shared__ int   us[4][8];
    __shared__ float wbs[4][8];
    int w = tid >> 6, lane = tid & 63;
    int p = bid * 4 + w;
    int b = p >> 10;
    float v = dat_t[((size_t)p << 6) + lane];
    if (lane < NVERT){
      int code = codes_pv[p * NVERT + lane];
      const int* hc = hash_code + b * CAP;
      uint32_t h = hslot(code);
      while (hc[h] != code) h = (h + 1) & CAPMASK;
      int uid = hash_uid[b * CAP + h];
      us[w][lane]  = uid;
      wbs[w][lane] = bary_pv[p * NVERT + lane];
      idx_pv[p * NVERT + lane] = uid;
    }
    __syncthreads();
    int rot = p % NVERT;                     // stagger to spread same-row atomics
    #pragma unroll
    for (int kq = 0; kq < NVERT; kq++){
      int kk = kq + rot; if (kk >= NVERT) kk -= NVERT;
      atomicAdd(&table[(((size_t)(b * M0 + us[w][kk])) << 6) + lane], v * wbs[w][kk]);
    }
  } else {
    // ---- neighbor uid lookup: one thread per (vertex, filter-offset) ----
    int e = (bid - BATCH * NPTS / 4) * 256 + tid;   // [0, BATCH*M0*32)
    int f = e & 31;
    int idx = e >> 5;                               // b*M0 + m
    int b = idx / M0, m = idx - b * M0;
    int g = ZROW;
    if (f < NF && m < ucount[b]){
      const int* uk = ukeys + ((size_t)idx) * DD;
      int pc = __popc(f);
      int code = 0;
      #pragma unroll
      for (int j = 0; j < DD; j++){
        int key = uk[j] + 5 * ((f >> j) & 1) - pc;
        key = min(63, max(-64, key));
        code += (key + 64) << (7 * j);
      }
      const int* hc = hash_code + b * CAP;
      uint32_t h = hslot(code);
      while (true){
        int v = hc[h];
        if (v == code){ g = b * M0 + hash_uid[b * CAP + h]; break; }
        if (v == SENTV) break;
        h = (h + 1) & CAPMASK;
      }
    }
    nuid[e] = g;
  }
}

// ============ table fp32 -> bf16 (+ zero row) ==============================
__global__ void k_tobf(const float* __restrict__ table, unsigned short* __restrict__ table_bf){
  int g = blockIdx.x * blockDim.x + threadIdx.x;
  size_t base = (size_t)g * 8;
  const float4* s4 = (const float4*)(table + base);
  float4 x = s4[0], y = s4[1];
  bf16x8 v;
  v[0] = (short)f2bf(x.x); v[1] = (short)f2bf(x.y);
  v[2] = (short)f2bf(x.z); v[3] = (short)f2bf(x.w);
  v[4] = (short)f2bf(y.x); v[5] = (short)f2bf(y.y);
  v[6] = (short)f2bf(y.z); v[7] = (short)f2bf(y.w);
  *(bf16x8*)(table_bf + base) = v;
  if (g < 8){
    bf16x8 z = {0,0,0,0,0,0,0,0};
    *(bf16x8*)(table_bf + ((size_t)ZROW << 6) + g * 8) = z;
  }
}

// ============ convolution: 8 waves, 2-way k-split, barrier-free MFMA ======
__launch_bounds__(512)
__global__ void k_conv(const int* __restrict__ ucount, const int* __restrict__ nuid,
                       const unsigned short* __restrict__ table_bf,
                       const unsigned short* __restrict__ bp,
                       float* __restrict__ out_lat){
  __shared__ int gidx_s[64 * 33];
  __shared__ float red[4][64][17];

  int blk = blockIdx.x;
  int b   = blk / (M0 / 64);
  int m0  = (blk % (M0 / 64)) * 64;
  if (m0 >= ucount[b]) return;

  int tid = threadIdx.x;
  {
    int base = (b * M0 + m0) << 5;
    #pragma unroll
    for (int i = 0; i < 4; i++){
      int idx = tid + i * 512;
      gidx_s[(idx >> 5) * 33 + (idx & 31)] = nuid[base + idx];
    }
  }
  __syncthreads();

  int lane = tid & 63, wave = tid >> 6;
  int wm = wave & 1, wo = (wave >> 1) & 1, wk = wave >> 2;
  int arow = wm * 32 + (lane & 15);
  int acol = (lane >> 4) * 8;
  int bcol = wo * 32 + (lane & 15);
  const unsigned short* bpp0 = bp + (size_t)bcol * KTOT + acol;
  const unsigned short* bpp1 = bpp0 + (size_t)16 * KTOT;

  f32x4 acc00 = {0.f,0.f,0.f,0.f}, acc01 = {0.f,0.f,0.f,0.f};
  f32x4 acc10 = {0.f,0.f,0.f,0.f}, acc11 = {0.f,0.f,0.f,0.f};

  int ks0 = wk * 32, ks1 = wk ? 62 : 32;
  #pragma unroll 4
  for (int ks = ks0; ks < ks1; ks++){
    int f  = ks >> 1;
    int c0 = (ks & 1) << 5;
    int g0 = gidx_s[arow * 33 + f];
    int g1 = gidx_s[(arow + 16) * 33 + f];
    bf16x8 a0 = *(const bf16x8*)(table_bf + (((size_t)g0) << 6) + c0 + acol);
    bf16x8 a1 = *(const bf16x8*)(table_bf + (((size_t)g1) << 6) + c0 + acol);
    bf16x8 b0 = *(const bf16x8*)(bpp0 + (ks << 5));
    bf16x8 b1 = *(const bf16x8*)(bpp1 + (ks << 5));
    acc00 = __builtin_amdgcn_mfma_f32_16x16x32_bf16(a0, b0, acc00, 0, 0, 0);
    acc01 = __builtin_amdgcn_mfma_f32_16x16x32_bf16(a0, b1, acc01, 0, 0, 0);
    acc10 = __builtin_amdgcn_mfma_f32_16x16x32_bf16(a1, b0, acc10, 0, 0, 0);
    acc11 = __builtin_amdgcn_mfma_f32_16x16x32_bf16(a1, b1, acc11, 0, 0, 0);
  }

  int wl = wave & 3;
  if (wk == 1){
    #pragma unroll
    for (int q = 0; q < 4; q++){
      red[wl][lane][q]      = acc00[q];
      red[wl][lane][4 + q]  = acc01[q];
      red[wl][lane][8 + q]  = acc10[q];
      red[wl][lane][12 + q] = acc11[q];
    }
  }
  __syncthreads();
  if (wk == 0){
    #pragma unroll
    for (int q = 0; q < 4; q++){
      acc00[q] += red[wl][lane][q];
      acc01[q] += red[wl][lane][4 + q];
      acc10[q] += red[wl][lane][8 + q];
      acc11[q] += red[wl][lane][12 + q];
    }
    // C/D layout: col = lane&15, row = (lane>>4)*4 + q (m89-verified)
    int q4 = (lane >> 4) * 4, col = lane & 15;
    #pragma unroll
    for (int i = 0; i < 2; i++){
      f32x4 ai0 = (i == 0) ? acc00 : acc10;
      f32x4 ai1 = (i == 0) ? acc01 : acc11;
      #pragma unroll
      for (int q = 0; q < 4; q++){
        int m = m0 + wm * 32 + i * 16 + q4 + q;
        float* orow = out_lat + (((size_t)(b * M0 + m)) << 6);
        orow[wo * 32 + col]      = ai0[q];
        orow[wo * 32 + 16 + col] = ai1[q];
      }
    }
  }
}

// ============ slice + bias + transpose to [b][o][n], 32-row tiles =========
__global__ void k_slice(const float* __restrict__ bary_pv, const int* __restrict__ idx_pv,
                        const float* __restrict__ out_lat, const float* __restrict__ bias,
                        const float* __restrict__ bmul, float* __restrict__ out){
  __shared__ float tile[32][65];
  int b = blockIdx.x >> 5, n0 = (blockIdx.x & 31) * 32;
  int tid = threadIdx.x;
  int wave = tid >> 6, o = tid & 63;
  float bo = bias[o];
  #pragma unroll
  for (int i = 0; i < 8; i++){
    int n = wave * 8 + i;
    int p = (b << 10) + n0 + n;
    float acc = bo * bmul[n0 + n];
    int base = p * NVERT;
    #pragma unroll
    for (int kk = 0; kk < NVERT; kk++){
      int u = idx_pv[base + kk];
      acc += bary_pv[base + kk] * out_lat[(((size_t)(b * M0 + u)) << 6) + o];
    }
    tile[n][o] = acc;
  }
  __syncthreads();
  int nl = tid & 31, ob = (tid >> 5) * 8;
  #pragma unroll
  for (int i = 0; i < 8; i++){
    int o2 = ob + i;
    out[(((size_t)b * 64 + o2) << 10) + n0 + nl] = tile[nl][o2];
  }
}

extern "C" void kernel_launch(void* const* d_in, const int* in_sizes, int n_in,
                              void* d_out, int out_size, void* d_ws, size_t ws_size,
                              hipStream_t stream){
  const float* data = (const float*)d_in[0];
  const float* feat = (const float*)d_in[1];
  const float* wk   = (const float*)d_in[2];
  const float* bias = (const float*)d_in[3];
  const float* bmul = (const float*)d_in[4];
  float* out = (float*)d_out;

  char* ws = (char*)d_ws;
  size_t off = 0;
  auto alloc = [&](size_t bytes){
    void* p = ws + off;
    off = (off + bytes + 255) & ~(size_t)255;
    return p;
  };
  int*   codes_pv = (int*)  alloc((size_t)BATCH * M0 * 4);
  float* bary_pv  = (float*)alloc((size_t)BATCH * M0 * 4);
  int*   idx_pv   = (int*)  alloc((size_t)BATCH * M0 * 4);
  int*   hash_code= (int*)  alloc((size_t)BATCH * CAP * 4);
  int*   hash_uid = (int*)  alloc((size_t)BATCH * CAP * 4);
  int*   ucount   = (int*)  alloc(256);
  int*   ukeys    = (int*)  alloc((size_t)BATCH * M0 * DD * 4);
  float* table    = (float*)alloc((size_t)BATCH * M0 * CIN * 4);
  float* out_lat  = (float*)alloc((size_t)BATCH * M0 * COUT * 4);
  unsigned short* bp       = (unsigned short*)alloc((size_t)COUT * KTOT * 2);
  unsigned short* table_bf = (unsigned short*)alloc(((size_t)BATCH * M0 + 8) * CIN * 2);
  float* dat_t    = (float*)alloc((size_t)BATCH * NPTS * CIN * 4);
  int*   nuid     = (int*)  alloc((size_t)BATCH * M0 * 32 * 4);

  k_setup <<<1024, 256, 0, stream>>>(wk, data, hash_code, hash_uid, ucount,
                                     (float4*)table, bp, dat_t);
  k_pmath <<<BATCH * M0 / 256, 256, 0, stream>>>(feat, codes_pv, bary_pv);
  k_insert<<<BATCH * M0 / 256, 256, 0, stream>>>(codes_pv, hash_code, hash_uid, ucount, ukeys);
  k_sn    <<<BATCH * NPTS / 4 + BATCH * M0 * 32 / 256, 256, 0, stream>>>(
            dat_t, codes_pv, bary_pv, hash_code, hash_uid, ucount, ukeys,
            idx_pv, table, nuid);
  k_tobf  <<<BATCH * M0 * CIN / 8 / 256, 256, 0, stream>>>(table, table_bf);
  k_conv  <<<BATCH * (M0 / 64), 512, 0, stream>>>(ucount, nuid, table_bf, bp, out_lat);
  k_slice <<<BATCH * 32, 256, 0, stream>>>(bary_pv, idx_pv, out_lat, bias, bmul, out);
}